// Round 9
// baseline (425.852 us; speedup 1.0000x reference)
//
#include <hip/hip_runtime.h>
#include <stdint.h>
#include <stddef.h>

// ---------------------------------------------------------------------------
// BayesianDTW forward on MI355X — R9 = R7 (proven) with the double-lse3
// refactored to ONE exp2 level + ONE log2 level per step (chain 4L -> 2L).
//   uA = aA + log2(sA),  aA = m1 + wA*log2e, m1 = max3(topA, lf, tl),
//   sA = exp2(topA-m1)+exp2(lf-m1)+exp2(tl-m1)            // sA in [1,3]
//   uB = m2 + wB*log2e + log2(sB), m2 = max3(topB, aA, topA),
//   sB = exp2(topB-m2) + sA*exp2(aA-m2) + exp2(topA-m2)   // sB in [1,5]
// (2^uA = sA*2^aA, so sB*2^m2 = 2^topB + 2^uA + 2^topA — exact identity;
//  m2 within log2(3) of the true max -> exp2 args <= +1.585, no overflow.)
// Everything else byte-identical to R7: 32x8 stripes, 1 wave, 2 cols/lane,
// skewed systolic wavefront, uncached edge dup + tagged flags, delayed
// publish under vmcnt(1), hidden poll, W ring via global_load_lds.
// Linear-domain variants (R4/R6/R8) all produced inf/NaN — abandoned.
// ---------------------------------------------------------------------------

#define NBATCH  32
#define NA      512
#define NB      1024
#define NSTRIPE 8
#define SW      128          // cols per stripe
#define CH      16           // rows per chunk
#define NCHUNK  (NA / CH)    // 32
#define LSTR    128          // LDS row stride (floats)
#define OROWS   513
#define OCOLS   1025
#define FSTRIDE 32           // flag padding: 128 B

#define NEGV    (-1e20f)
#define LOG2E   (1.4426950408889634f)
#define LN2     (0.6931471805599453f)
#define NEG2    (-1.4426950408889634e20f)   // NEGV in log2 units
#define FLAGTAG 0x5A000000u

#define EXP2F(x) __builtin_amdgcn_exp2f(x)   // v_exp_f32: 2^x
#define LOG2F(x) __builtin_amdgcn_logf(x)    // v_log_f32: log2(x)

__device__ __forceinline__ void gl_lds(const float* g, float* l) {
    __builtin_amdgcn_global_load_lds(
        (const __attribute__((address_space(1))) void*)g,
        (__attribute__((address_space(3))) void*)l, 4, 0, 0);
}

__device__ __forceinline__ float rdlane(float v, int l) {
    return __int_as_float(__builtin_amdgcn_readlane(__float_as_int(v), l));
}

// lane i <- lane i-1, pure VALU: DPP row_shr:1 + readlane patches (16/32/48).
__device__ __forceinline__ float lane_shr1(float x, int lane) {
    int xi  = __float_as_int(x);
    int shr = __builtin_amdgcn_update_dpp(0, xi, 0x111, 0xf, 0xf, true);
    float v = __int_as_float(shr);
    float a15 = rdlane(x, 15), a31 = rdlane(x, 31), a47 = rdlane(x, 47);
    v = (lane == 16) ? a15 : v;
    v = (lane == 32) ? a31 : v;
    v = (lane == 48) ? a47 : v;
    return v;
}

__device__ __forceinline__ unsigned int ld_flag(unsigned int* fp) {
    return __hip_atomic_load(fp, __ATOMIC_RELAXED, __HIP_MEMORY_SCOPE_AGENT);
}
__device__ __forceinline__ void st_flag(unsigned int* fp, unsigned int v) {
    __hip_atomic_store(fp, v, __ATOMIC_RELAXED, __HIP_MEMORY_SCOPE_AGENT);
}
__device__ __forceinline__ float ld_edge(const float* p) {
    return __hip_atomic_load((float*)p, __ATOMIC_RELAXED, __HIP_MEMORY_SCOPE_AGENT);
}
__device__ __forceinline__ void st_edge(float* p, float v) {
    __hip_atomic_store(p, v, __ATOMIC_RELAXED, __HIP_MEMORY_SCOPE_AGENT);
}

__device__ __forceinline__ void wait_flag(unsigned int* fp, unsigned int need) {
    for (int k = 0; k < (1 << 22); ++k) {
        unsigned int v = ld_flag(fp);
        if ((v >> 24) == 0x5Au && (v & 0x00FFFFFFu) >= need) break;
    }
    asm volatile("" ::: "memory");
}

__global__ __launch_bounds__(64, 1)
void dtw_pipe(const float* __restrict__ W, float* __restrict__ out,
              unsigned int* __restrict__ flags)
{
    __shared__ float lds_w[128 * LSTR];   // W ring: row r at slot r&127
    __shared__ float lds_o[128 * LSTR];   // output ring (ln units, final)

    const int lane = (int)threadIdx.x;
    const int bid  = (int)blockIdx.x;             // s*32 + b
    const int b    = bid & (NBATCH - 1);
    const int s    = bid >> 5;

    const float*  Wb  = W + ((size_t)b * NA) * NB + s * SW;
    float*        ob  = out + (size_t)b * OROWS * OCOLS;
    unsigned int* fmy = flags + (size_t)bid * FSTRIDE;
    unsigned int* fup = flags + (size_t)(bid - NBATCH) * FSTRIDE;

    // ---- boundary cells of output ----
    ob[s * SW + 1 + lane]      = NEGV;
    ob[s * SW + 1 + 64 + lane] = NEGV;
    if (s == 0) {
        if (lane == 0) ob[0] = 0.0f;
        for (int r = lane; r < NA; r += 64)
            ob[(size_t)(r + 1) * OCOLS] = NEGV;
    }

    // ---- prestage W chunks 0..2 (rows 0..47) ----
    for (int q = 0; q < 3; ++q) {
        const float* wsrc = Wb + (size_t)q * CH * NB;
        for (int rr = 0; rr < CH; ++rr) {
            const int slot = q * CH + rr;
            gl_lds(wsrc + (size_t)rr * NB + lane,      &lds_w[slot * LSTR]);
            gl_lds(wsrc + (size_t)rr * NB + 64 + lane, &lds_w[slot * LSTR + 64]);
        }
    }

    // ---- edge prefetch (log2 units; lanes 0..15 hold 16 rows each) ----
    float evcur = -1e30f, evnxt = -1e30f, lres = -1e30f;
    if (s > 0) {
        wait_flag(fup, 1u);
        if (lane < CH)
            evcur = ld_edge(&ob[(size_t)(1 + lane) * OCOLS + s * SW]) * LOG2E;
        wait_flag(fup, 2u);
        if (lane < CH)
            evnxt = ld_edge(&ob[(size_t)(CH + 1 + lane) * OCOLS + s * SW]) * LOG2E;
        wait_flag(fup, 3u);
        if (lane < CH)
            lres  = ld_edge(&ob[(size_t)(2 * CH + 1 + lane) * OCOLS + s * SW]) * LOG2E;
    }

    asm volatile("s_waitcnt vmcnt(0)" ::: "memory");   // gl_lds + edges done

    // ---- systolic state (log2 units, R3/R7-proven domain) ----
    float topA = NEG2, topB = NEG2;   // mu[i-1, jA], mu[i-1, jB] (log2)
    float sh_in = NEG2;               // left neighbor's uB from prev step
    float tl_reg = NEG2;              // mu[i-1, jA-1]
    float ev_im1 = (s == 0) ? 0.0f : NEG2;  // lane0 topleft: mu[0,128s]·log2e
    unsigned int fpoll = 0;

    // W prefetch: w_cur = row r(t), w_nx1 = row r(t)+1; issue +2 each step
    float2 w_cur = *(const float2*)&lds_w[((0 - lane) & 127) * LSTR + 2 * lane];
    float2 w_nx1 = *(const float2*)&lds_w[((1 - lane) & 127) * LSTR + 2 * lane];

    auto step = [&](int m_, int tt) {
        const int t = (m_ << 4) + tt;
        const int r = t - lane;
        if (tt == 1 && s > 0) fpoll = ld_flag(fup);      // hidden poll
        // prefetch W row r+2 (2-step lead > ds latency)
        float2 w_pre = *(const float2*)&lds_w[((r + 2) & 127) * LSTR + 2 * lane];
        // edge broadcast: wave-uniform immediate lane index -> v_readlane
        const float ev_i = rdlane(evcur, tt);
        // ---- carried chain (one exp2 level + one log2 level) ----
        const float lf = (lane == 0) ? ev_i   : sh_in;   // mu[i, jA-1]
        const float tl = (lane == 0) ? ev_im1 : tl_reg;  // mu[i-1, jA-1]
        const float m1  = fmaxf(fmaxf(topA, lf), tl);
        const float eA0 = EXP2F(topA - m1);
        const float sA  = eA0 + EXP2F(lf - m1) + EXP2F(tl - m1);   // [1,3]
        const float aA  = fmaf(w_cur.x, LOG2E, m1);      // uA = aA + log2 sA
        const float m2  = fmaxf(fmaxf(topB, aA), topA);  // >= true max - 1.585
        const float sB  = EXP2F(topB - m2) + sA * EXP2F(aA - m2)
                        + EXP2F(topA - m2);              // [1,5]
        const float uA  = aA + LOG2F(sA);
        const float uB  = fmaf(w_cur.y, LOG2E, m2) + LOG2F(sB);
        const bool on = (r >= 0);
        if (on & (r < NA)) {                             // off-chain store (ln)
            *(float2*)&lds_o[(r & 127) * LSTR + 2 * lane]
                = make_float2(uA * LN2, uB * LN2);
        }
        topA   = on ? uA : NEG2;
        topB   = on ? uB : NEG2;
        tl_reg = on ? lf : NEG2;
        ev_im1 = ev_i;
        sh_in  = lane_shr1(uB, lane);                    // pure-VALU pass
        w_cur = w_nx1; w_nx1 = w_pre;
    };

    for (int m = 0; m < 35; ++m) {
        #pragma unroll
        for (int tt = 0; tt < 16; ++tt) step(m, tt);

        // ================= chunk boundary (t = 16m+15 done) =================
        const int f = m - 4;                  // chunk fully complete (skew 63)
        if (s < NSTRIPE - 1 && f >= 0 && lane < CH) {
            const int rw = (f << 4) + lane;
            const float evl = lds_o[(rw & 127) * LSTR + 127];
            st_edge(ob + (size_t)(rw + 1) * OCOLS + (s + 1) * SW, evl);
        }
        // vmcnt(1): chunk f-1's edge stores visible; publish flag f (<= f-1).
        asm volatile("s_waitcnt vmcnt(1)" ::: "memory");
        if (s < NSTRIPE - 1 && f >= 1 && lane == 0)
            st_flag(fmy, FLAGTAG + (unsigned)f);
        if (f >= 0) {
            #pragma unroll
            for (int rr = 0; rr < CH; ++rr) {
                const int rw = (f << 4) + rr;
                const float v0 = lds_o[(rw & 127) * LSTR + lane];
                const float v1 = lds_o[(rw & 127) * LSTR + 64 + lane];
                float* orow = ob + (size_t)(rw + 1) * OCOLS + s * SW + 1;
                orow[lane]      = v0;
                orow[64 + lane] = v1;
            }
        }
        // rotate edge regs; poll + load chunk m+3 (need m+4, polled at tt==1)
        evcur = evnxt; evnxt = lres;
        const int c = m + 3;
        if (s > 0 && c < NCHUNK) {
            const unsigned need = (unsigned)(m + 4);
            if (!((fpoll >> 24) == 0x5Au && (fpoll & 0x00FFFFFFu) >= need))
                wait_flag(fup, need);
            lres = -1e30f;
            if (lane < CH)
                lres = ld_edge(&ob[(size_t)((c << 4) + 1 + lane) * OCOLS + s * SW])
                       * LOG2E;
        }
        // stage W chunk m+3
        if (c < NCHUNK) {
            const float* wsrc = Wb + (size_t)(c << 4) * NB;
            #pragma unroll
            for (int rr = 0; rr < CH; ++rr) {
                const int slot = ((c << 4) + rr) & 127;
                gl_lds(wsrc + (size_t)rr * NB + lane,      &lds_w[slot * LSTR]);
                gl_lds(wsrc + (size_t)rr * NB + 64 + lane, &lds_w[slot * LSTR + 64]);
            }
        }
    }

    // tail steps t = 560..574 (lane 63 finishes row 511 at t=574)
    #pragma unroll
    for (int tt = 0; tt < 15; ++tt) step(35, tt);

    // ---- epilogue: chunk 31 ----
    {
        const int f = NCHUNK - 1;
        if (s < NSTRIPE - 1 && lane < CH) {
            const int rw = (f << 4) + lane;
            const float evl = lds_o[(rw & 127) * LSTR + 127];
            st_edge(ob + (size_t)(rw + 1) * OCOLS + (s + 1) * SW, evl);
        }
        asm volatile("s_waitcnt vmcnt(1)" ::: "memory");
        if (s < NSTRIPE - 1 && lane == 0)
            st_flag(fmy, FLAGTAG + (unsigned)(NCHUNK - 1));   // chunks 0..30
        #pragma unroll
        for (int rr = 0; rr < CH; ++rr) {
            const int rw = (f << 4) + rr;
            const float v0 = lds_o[(rw & 127) * LSTR + lane];
            const float v1 = lds_o[(rw & 127) * LSTR + 64 + lane];
            float* orow = ob + (size_t)(rw + 1) * OCOLS + s * SW + 1;
            orow[lane]      = v0;
            orow[64 + lane] = v1;
        }
        asm volatile("s_waitcnt vmcnt(0)" ::: "memory");
        if (s < NSTRIPE - 1 && lane == 0)
            st_flag(fmy, FLAGTAG + (unsigned)NCHUNK);         // all 32 chunks
    }
}

extern "C" void kernel_launch(void* const* d_in, const int* in_sizes, int n_in,
                              void* d_out, int out_size, void* d_ws, size_t ws_size,
                              hipStream_t stream) {
    const float*  W     = (const float*)d_in[0];
    float*        out   = (float*)d_out;
    unsigned int* flags = (unsigned int*)d_ws;
    (void)in_sizes; (void)n_in; (void)out_size; (void)ws_size;
    hipLaunchKernelGGL(dtw_pipe, dim3(NBATCH * NSTRIPE), dim3(64), 0, stream,
                       W, out, flags);
}